// Round 1
// 856.593 us; speedup vs baseline: 1.1677x; 1.1677x over previous
//
#include <hip/hip_runtime.h>
#include <hip/hip_bf16.h>

typedef __hip_bfloat16 bf16;
typedef __attribute__((ext_vector_type(8))) short bf16x8;   // 8 bf16 = 4 VGPRs (A/B frag)
typedef __attribute__((ext_vector_type(4))) float floatx4;  // C/D frag
typedef __attribute__((ext_vector_type(4))) unsigned short u16x4;

#define SCALE 0.17677669529663687f  // 32^-0.5
#define MFMA16 __builtin_amdgcn_mfma_f32_16x16x32_bf16

__device__ __forceinline__ short f2bs(float x) {
  union { bf16 h; short s; } u; u.h = __float2bfloat16(x); return u.s;
}
__device__ __forceinline__ float ldf(const void* p, size_t i, bool f32) {
  return f32 ? ((const float*)p)[i] : __bfloat162float(((const bf16*)p)[i]);
}
__device__ __forceinline__ float bs2f(unsigned short u) {
  union { unsigned short u; bf16 h; } v; v.u = u; return __bfloat162float(v.h);
}
// idx is a multiple of 8 at every call site -> float4-aligned
__device__ __forceinline__ bf16x8 load8(const void* p, size_t idx, bool f32) {
  if (f32) {
    const floatx4* fp = (const floatx4*)((const float*)p + idx);
    floatx4 a = fp[0], b = fp[1];
    bf16x8 r;
    r[0] = f2bs(a[0]); r[1] = f2bs(a[1]); r[2] = f2bs(a[2]); r[3] = f2bs(a[3]);
    r[4] = f2bs(b[0]); r[5] = f2bs(b[1]); r[6] = f2bs(b[2]); r[7] = f2bs(b[3]);
    return r;
  }
  return *(const bf16x8*)((const bf16*)p + idx);
}

// ---------- dtype detector: fp32 data viewed as bf16 words has ~44% huge exponents ----------
__global__ void detect_dtype(const unsigned short* __restrict__ q_w_u16, int* __restrict__ flag) {
  int tid = threadIdx.x;  // 64 threads
  int cnt = 0;
  for (int i = tid; i < 4096; i += 64) {
    int e = (q_w_u16[i] >> 7) & 0xFF;
    cnt += (e >= 145);  // |x| >= 2^18: never for N(0,1) bf16
  }
  #pragma unroll
  for (int off = 32; off; off >>= 1) cnt += __shfl_down(cnt, off);
  if (tid == 0) *flag = (cnt >= 16) ? 1 : 0;
}

// ---------- weight transpose: dst[n][k] = src[k][n], K = 256 rows ----------
__global__ __launch_bounds__(256) void transpose_w(const void* __restrict__ src,
                                                   bf16* __restrict__ dst, int N,
                                                   const int* __restrict__ flagp) {
  __shared__ bf16 t[32][33];
  const bool f = (*flagp != 0);
  int bx = blockIdx.x * 32;  // n base
  int by = blockIdx.y * 32;  // k base
  int x = threadIdx.x & 31, y = threadIdx.x >> 5;
  #pragma unroll
  for (int yy = y; yy < 32; yy += 8)
    t[yy][x] = __float2bfloat16(ldf(src, (size_t)(by + yy) * N + bx + x, f));
  __syncthreads();
  #pragma unroll
  for (int yy = y; yy < 32; yy += 8)
    dst[(size_t)(bx + yy) * 256 + by + x] = t[x][yy];
}

// ---------- bias gather-expand into MFMA-fragment layout ----------
// dst[h][qb(16)][kt(36)][l16(16)][q4(4)][r(4)] = table[rel[q][k]][h]
// where q = qb*16 + q4*4 + r, k = kt*16 + l16.
// A lane (q4,l16) then reads its 4 C-operand values as ONE 8B load.
__global__ __launch_bounds__(256) void bias_expand(const void* __restrict__ table,
                                                   const int* __restrict__ relidx,
                                                   bf16* __restrict__ biasFb,
                                                   const int* __restrict__ flagp) {
  const bool f = (*flagp != 0);
  int i = blockIdx.x * 256 + threadIdx.x;  // over 256*576 = 147456 (q*576+k)
  int q = i / 576, k = i - q * 576;
  int idx = relidx[i];
  int qb = q >> 4, q4 = (q >> 2) & 3, r = q & 3;
  int kt = k >> 4, l16 = k & 15;
  size_t off = ((size_t)qb * 36 + kt) * 256 + l16 * 16 + q4 * 4 + r;
  #pragma unroll
  for (int h = 0; h < 8; h++)
    biasFb[(size_t)h * 147456 + off] = __float2bfloat16(ldf(table, (size_t)idx * 8 + h, f));
}

// ---------- GEMM: C[m][n] = A[a_off + m][0:256] . BT[n][0:256] + bias[n] ----------
// EPI 0: store to C (d_out, dtype per flag) at c_off, row stride 256   (out proj)
// EPI 1: store bf16 (v*SCALE), row stride 256                          (q proj)
// EPI 2: ncol<256 -> Kb[m][256] bf16; ncol>=256 -> Vt[w][h][d][n] bf16 (kv proj)
// A dtype: EPI==0 -> always bf16 (internal); else per flag.
template <int EPI>
__global__ __launch_bounds__(256) void gemm_bt(const void* __restrict__ A, size_t a_off,
                                               const bf16* __restrict__ BT,
                                               const void* __restrict__ bias,
                                               void* __restrict__ C, size_t c_off,
                                               bf16* __restrict__ C2,
                                               const int* __restrict__ flagp) {
  __shared__ __align__(16) bf16 As[128 * 40];  // +8 pad kills b128 bank conflicts
  __shared__ __align__(16) bf16 Bs[128 * 40];
  const bool f = (*flagp != 0);
  const bool af = (EPI == 0) ? false : f;  // A dtype (Obuf is internal bf16)
  const int tid = threadIdx.x;
  const int wave = tid >> 6, lane = tid & 63;
  const int q4 = lane >> 4, l16 = lane & 15;
  const int m0 = blockIdx.x * 128, n0 = blockIdx.y * 128;
  const int wm = (wave & 1) * 64, wn = (wave >> 1) * 64;  // 2x2 waves of 64x64
  const int sr = tid >> 2, sc = (tid & 3) * 8;
  floatx4 acc[4][4];
  #pragma unroll
  for (int i = 0; i < 4; i++)
    #pragma unroll
    for (int j = 0; j < 4; j++) acc[i][j] = (floatx4){0.f, 0.f, 0.f, 0.f};

  const size_t abase = a_off + (size_t)(m0 + sr) * 256 + sc;
  const bf16* Bp = BT + (size_t)(n0 + sr) * 256 + sc;
  for (int k0 = 0; k0 < 256; k0 += 32) {
    *(bf16x8*)&As[sr * 40 + sc]        = load8(A, abase + k0, af);
    *(bf16x8*)&As[(sr + 64) * 40 + sc] = load8(A, abase + 64 * 256 + k0, af);
    *(bf16x8*)&Bs[sr * 40 + sc]        = *(const bf16x8*)(Bp + k0);
    *(bf16x8*)&Bs[(sr + 64) * 40 + sc] = *(const bf16x8*)(Bp + 64 * 256 + k0);
    __syncthreads();
    bf16x8 afr[4], bfr[4];
    #pragma unroll
    for (int i = 0; i < 4; i++)
      afr[i] = *(const bf16x8*)&As[(wm + i * 16 + l16) * 40 + q4 * 8];
    #pragma unroll
    for (int j = 0; j < 4; j++)
      bfr[j] = *(const bf16x8*)&Bs[(wn + j * 16 + l16) * 40 + q4 * 8];
    #pragma unroll
    for (int i = 0; i < 4; i++)
      #pragma unroll
      for (int j = 0; j < 4; j++)
        acc[i][j] = MFMA16(afr[i], bfr[j], acc[i][j], 0, 0, 0);
    __syncthreads();
  }
  // epilogue: lane holds rows quad*4+r, col lane&15 of each 16x16 tile
  #pragma unroll
  for (int i = 0; i < 4; i++) {
    #pragma unroll
    for (int j = 0; j < 4; j++) {
      int mrow = m0 + wm + i * 16 + q4 * 4;
      int ncol = n0 + wn + j * 16 + l16;
      float bv = ldf(bias, ncol, f);
      #pragma unroll
      for (int r = 0; r < 4; r++) {
        float v = acc[i][j][r] + bv;
        int m_e = mrow + r;
        if (EPI == 0) {
          size_t oi = c_off + (size_t)m_e * 256 + ncol;
          if (f) ((float*)C)[oi] = v;
          else   ((bf16*)C)[oi] = __float2bfloat16(v);
        } else if (EPI == 1) {
          ((bf16*)C)[(size_t)m_e * 256 + ncol] = __float2bfloat16(v * SCALE);
        } else {
          if (ncol < 256) {
            ((bf16*)C)[(size_t)m_e * 256 + ncol] = __float2bfloat16(v);
          } else {
            int cc = ncol - 256;
            int hh = cc >> 5, dd = cc & 31;
            int bb = m_e / 576;            // chunk-local window
            int nn = m_e - bb * 576;
            C2[(((size_t)bb * 8 + hh) * 32 + dd) * 576 + nn] = __float2bfloat16(v);
          }
        }
      }
    }
  }
}

// ---------- attention v2: flash-style online softmax, no barriers ----------
// block = (b, h, qc) after XCD swizzle; wave owns 16 q-rows; 9 k-tiles of 64.
// Per-wave P buffer in LDS (in-order DS => no __syncthreads anywhere).
__global__ __launch_bounds__(256, 4) void attn(const bf16* __restrict__ Q,     // [W*256][256] pre-scaled
                                               const bf16* __restrict__ Kb,    // [W*576][256]
                                               const bf16* __restrict__ Vt,    // [W][8][32][576]
                                               const bf16* __restrict__ biasF, // fragment layout, see bias_expand
                                               bf16* __restrict__ O,           // [W*256][256]
                                               int nwg) {
  __shared__ __align__(16) bf16 P[4][16][88];  // 16 x 64 (+24 pad): rows 176B (16B-aligned, q4 spread)
  const int tid = threadIdx.x, wave = tid >> 6, lane = tid & 63;
  const int q4 = lane >> 4, l16 = lane & 15;
  // bijective XCD swizzle: consecutive physical blocks round-robin XCDs;
  // map so each XCD gets a contiguous logical range (same-b blocks share K/V in its L2)
  const int cpx = nwg >> 3;                    // nwg % 8 == 0 (W even)
  const int L = (blockIdx.x & 7) * cpx + (blockIdx.x >> 3);
  const int b = L >> 5, h = (L >> 2) & 7, qc = L & 3;
  const int q0 = qc * 64 + wave * 16;
  const int qb = qc * 4 + wave;

  // Q A-frag: row = lane&15, k(d) = quad*8+j  (one 16B load)
  bf16x8 qf = *(const bf16x8*)&Q[((size_t)b * 256 + q0 + l16) * 256 + h * 32 + q4 * 8];
  const bf16* kp = Kb + (size_t)b * 576 * 256 + h * 32 + q4 * 8;          // + k*256
  const bf16* vp = Vt + ((size_t)b * 8 + h) * 32 * 576 + q4 * 8;          // + d*576 + k
  const unsigned short* bp =
      (const unsigned short*)biasF + ((size_t)h * 16 + qb) * 9216 + l16 * 16 + q4 * 4;  // + kt*256

  float m[4] = {-1e30f, -1e30f, -1e30f, -1e30f};
  float l[4] = {0.f, 0.f, 0.f, 0.f};
  floatx4 o0 = (floatx4){0.f, 0.f, 0.f, 0.f};
  floatx4 o1 = (floatx4){0.f, 0.f, 0.f, 0.f};

  // prefetch tile 0 (K B-frags + bias C-frags)
  bf16x8 kf[4]; u16x4 bf[4];
  #pragma unroll
  for (int t = 0; t < 4; t++) {
    kf[t] = *(const bf16x8*)(kp + (size_t)(16 * t + l16) * 256);
    bf[t] = *(const u16x4*)(bp + t * 256);
  }

  #pragma unroll 1
  for (int it = 0; it < 9; it++) {
    const int k0 = it * 64;
    // V B-frags for this tile (issued early; consumed after softmax ~300 VALU later)
    bf16x8 vf[2][2];
    #pragma unroll
    for (int ks = 0; ks < 2; ks++) {
      vf[ks][0] = *(const bf16x8*)(vp + (size_t)l16 * 576 + k0 + ks * 32);
      vf[ks][1] = *(const bf16x8*)(vp + (size_t)(l16 + 16) * 576 + k0 + ks * 32);
    }
    // next-tile K/bias prefetch (covers global latency under this tile's compute)
    bf16x8 kn[4]; u16x4 bn[4];
    if (it < 8) {
      #pragma unroll
      for (int t = 0; t < 4; t++) {
        kn[t] = *(const bf16x8*)(kp + (size_t)(k0 + 64 + 16 * t + l16) * 256);
        bn[t] = *(const u16x4*)(bp + (it + 1) * 1024 + t * 256);
      }
    }
    // S = Q.K^T + bias : 4 MFMAs, lane holds rows q4*4+r, col l16 (+16t)
    floatx4 s[4];
    #pragma unroll
    for (int t = 0; t < 4; t++) {
      floatx4 c;
      #pragma unroll
      for (int r = 0; r < 4; r++) c[r] = bs2f(bf[t][r]);
      s[t] = MFMA16(qf, kf[t], c, 0, 0, 0);
    }
    // online softmax update + P write (P is per-wave: no barrier, DS in-order)
    #pragma unroll
    for (int r = 0; r < 4; r++) {
      float tm = fmaxf(fmaxf(s[0][r], s[1][r]), fmaxf(s[2][r], s[3][r]));
      #pragma unroll
      for (int off = 1; off < 16; off <<= 1) tm = fmaxf(tm, __shfl_xor(tm, off));
      float mn = fmaxf(m[r], tm);
      float sc = __expf(m[r] - mn);
      float rs = 0.f;
      #pragma unroll
      for (int t = 0; t < 4; t++) {
        float p = __expf(s[t][r] - mn);
        s[t][r] = p;
        rs += p;
      }
      #pragma unroll
      for (int off = 1; off < 16; off <<= 1) rs += __shfl_xor(rs, off);
      l[r] = l[r] * sc + rs;
      m[r] = mn;
      o0[r] *= sc; o1[r] *= sc;
      #pragma unroll
      for (int t = 0; t < 4; t++)
        P[wave][q4 * 4 + r][t * 16 + l16] = __float2bfloat16(s[t][r]);
    }
    // PV: A = P (row=l16, k contiguous), B = V^T frags
    bf16x8 pf0 = *(const bf16x8*)&P[wave][l16][q4 * 8];
    bf16x8 pf1 = *(const bf16x8*)&P[wave][l16][32 + q4 * 8];
    o0 = MFMA16(pf0, vf[0][0], o0, 0, 0, 0);
    o1 = MFMA16(pf0, vf[0][1], o1, 0, 0, 0);
    o0 = MFMA16(pf1, vf[1][0], o0, 0, 0, 0);
    o1 = MFMA16(pf1, vf[1][1], o1, 0, 0, 0);
    if (it < 8) {
      #pragma unroll
      for (int t = 0; t < 4; t++) { kf[t] = kn[t]; bf[t] = bn[t]; }
    }
  }
  // normalize + store
  bf16* op = O + ((size_t)b * 256 + q0 + q4 * 4) * 256 + h * 32;
  #pragma unroll
  for (int r = 0; r < 4; r++) {
    float inv = 1.f / l[r];
    op[(size_t)r * 256 + l16]      = __float2bfloat16(o0[r] * inv);
    op[(size_t)r * 256 + 16 + l16] = __float2bfloat16(o1[r] * inv);
  }
}

extern "C" void kernel_launch(void* const* d_in, const int* in_sizes, int n_in,
                              void* d_out, int out_size, void* d_ws, size_t ws_size,
                              hipStream_t stream) {
  const void* q_w    = d_in[0];
  const void* kv_w   = d_in[1];
  const void* q_Wm   = d_in[2];
  const void* q_b    = d_in[3];
  const void* kv_Wm  = d_in[4];
  const void* kv_b   = d_in[5];
  const void* proj_Wm= d_in[6];
  const void* proj_b = d_in[7];
  const void* btab   = d_in[8];
  const int*  relidx = (const int*)d_in[9];

  // ---- workspace layout (element offsets are dtype-agnostic) ----
  // flag 256 | WqT 131072 | WkvT 262144 | WpT 131072 | biasFb 2359296 | chunk buffers
  const size_t FIXED = 256 + 131072 + 262144 + 131072 + 2359296;  // 2,883,840
  int W = 2;
  {
    const int cand[8] = {256, 128, 64, 32, 16, 8, 4, 2};
    for (int i = 0; i < 8; i++) {
      if (ws_size >= FIXED + (size_t)cand[i] * 851968ULL) { W = cand[i]; break; }
    }
  }
  const int NCH = 256 / W;

  char* ws = (char*)d_ws;
  int*  flag  = (int*)(ws);
  bf16* WqT   = (bf16*)(ws + 256);
  bf16* WkvT  = (bf16*)(ws + 131328);
  bf16* WpT   = (bf16*)(ws + 393472);
  bf16* biasFb= (bf16*)(ws + 524544);
  char* cb    = ws + FIXED;
  const size_t qsz = (size_t)W * 131072ULL;   // W*256*256*2
  const size_t ksz = (size_t)W * 294912ULL;   // W*576*256*2
  bf16* Qs   = (bf16*)(cb);
  bf16* Kb   = (bf16*)(cb + qsz);
  bf16* Vt   = (bf16*)(cb + qsz + ksz);
  bf16* Obuf = (bf16*)(cb + qsz + 2 * ksz);

  detect_dtype<<<1, 64, 0, stream>>>((const unsigned short*)q_w, flag);
  transpose_w<<<dim3(8, 8),  256, 0, stream>>>(q_Wm,   WqT,  256, flag);
  transpose_w<<<dim3(16, 8), 256, 0, stream>>>(kv_Wm,  WkvT, 512, flag);
  transpose_w<<<dim3(8, 8),  256, 0, stream>>>(proj_Wm,WpT,  256, flag);
  bias_expand<<<576, 256, 0, stream>>>(btab, relidx, biasFb, flag);

  for (int c = 0; c < NCH; c++) {
    const size_t qoff = (size_t)c * W * 65536;    // elements
    const size_t koff = (size_t)c * W * 147456;   // elements
    // q projection (+scale): M = W*256, N = 256
    gemm_bt<1><<<dim3(2 * W, 2), 256, 0, stream>>>(q_w, qoff, WqT, q_b, Qs, 0, nullptr, flag);
    // kv projection: M = W*576, N = 512 (W even -> grid integral)
    gemm_bt<2><<<dim3((W * 576) / 128, 4), 256, 0, stream>>>(kv_w, koff, WkvT, kv_b, Kb, 0, Vt, flag);
    // attention: W windows * 8 heads * 4 q-chunks
    attn<<<W * 32, 256, 0, stream>>>(Qs, Kb, Vt, biasFb, Obuf, W * 32);
    // output projection: M = W*256, N = 256, store dtype per flag
    gemm_bt<0><<<dim3(2 * W, 2), 256, 0, stream>>>(Obuf, 0, WpT, proj_b, d_out, qoff, nullptr, flag);
  }
}

// Round 2
// 809.594 us; speedup vs baseline: 1.2355x; 1.0581x over previous
//
#include <hip/hip_runtime.h>
#include <hip/hip_bf16.h>

typedef __hip_bfloat16 bf16;
typedef __attribute__((ext_vector_type(8))) short bf16x8;   // 8 bf16 = 4 VGPRs (A/B frag)
typedef __attribute__((ext_vector_type(4))) float floatx4;  // C/D frag
typedef __attribute__((ext_vector_type(4))) unsigned short u16x4;

#define L2E 1.4426950408889634f
#define SCALE_L2E (0.17677669529663687f * 1.4426950408889634f)  // 32^-0.5 * log2(e)
#define MFMA16 __builtin_amdgcn_mfma_f32_16x16x32_bf16

__device__ __forceinline__ short f2bs(float x) {
  union { bf16 h; short s; } u; u.h = __float2bfloat16(x); return u.s;
}
__device__ __forceinline__ float ldf(const void* p, size_t i, bool f32) {
  return f32 ? ((const float*)p)[i] : __bfloat162float(((const bf16*)p)[i]);
}
__device__ __forceinline__ float bs2f(unsigned short u) {
  union { unsigned short u; bf16 h; } v; v.u = u; return __bfloat162float(v.h);
}
__device__ __forceinline__ unsigned int pkbf(float a, float b) {
  union { bf16 h; unsigned short s; } ua, ub;
  ua.h = __float2bfloat16(a); ub.h = __float2bfloat16(b);
  return (unsigned int)ua.s | ((unsigned int)ub.s << 16);
}
// idx is a multiple of 8 at every call site -> float4-aligned
__device__ __forceinline__ bf16x8 load8(const void* p, size_t idx, bool f32) {
  if (f32) {
    const floatx4* fp = (const floatx4*)((const float*)p + idx);
    floatx4 a = fp[0], b = fp[1];
    bf16x8 r;
    r[0] = f2bs(a[0]); r[1] = f2bs(a[1]); r[2] = f2bs(a[2]); r[3] = f2bs(a[3]);
    r[4] = f2bs(b[0]); r[5] = f2bs(b[1]); r[6] = f2bs(b[2]); r[7] = f2bs(b[3]);
    return r;
  }
  return *(const bf16x8*)((const bf16*)p + idx);
}

// ---------- dtype detector: fp32 data viewed as bf16 words has ~44% huge exponents ----------
__global__ void detect_dtype(const unsigned short* __restrict__ q_w_u16, int* __restrict__ flag) {
  int tid = threadIdx.x;  // 64 threads
  int cnt = 0;
  for (int i = tid; i < 4096; i += 64) {
    int e = (q_w_u16[i] >> 7) & 0xFF;
    cnt += (e >= 145);  // |x| >= 2^18: never for N(0,1) bf16
  }
  #pragma unroll
  for (int off = 32; off; off >>= 1) cnt += __shfl_down(cnt, off);
  if (tid == 0) *flag = (cnt >= 16) ? 1 : 0;
}

// ---------- weight transpose: dst[n][k] = src[k][n], K = 256 rows ----------
__global__ __launch_bounds__(256) void transpose_w(const void* __restrict__ src,
                                                   bf16* __restrict__ dst, int N,
                                                   const int* __restrict__ flagp) {
  __shared__ bf16 t[32][33];
  const bool f = (*flagp != 0);
  int bx = blockIdx.x * 32;  // n base
  int by = blockIdx.y * 32;  // k base
  int x = threadIdx.x & 31, y = threadIdx.x >> 5;
  #pragma unroll
  for (int yy = y; yy < 32; yy += 8)
    t[yy][x] = __float2bfloat16(ldf(src, (size_t)(by + yy) * N + bx + x, f));
  __syncthreads();
  #pragma unroll
  for (int yy = y; yy < 32; yy += 8)
    dst[(size_t)(bx + yy) * 256 + by + x] = t[x][yy];
}

// ---------- bias gather-expand into SWAPPED MFMA-fragment layout (S^T), *log2(e) ----------
// dst[h][qb(16)][kt(36)][ (q&15)(16) ][ (k&15)(16) ] = table[rel[q][k]][h] * log2e
// where q = qb*16 + (q&15), k = kt*16 + (k&15).
// attn lane (q4,l16) reads its 4 C values (kv = kt*16 + q4*4 + r) as ONE 8B load.
__global__ __launch_bounds__(256) void bias_expand(const void* __restrict__ table,
                                                   const int* __restrict__ relidx,
                                                   bf16* __restrict__ biasFb,
                                                   const int* __restrict__ flagp) {
  const bool f = (*flagp != 0);
  int i = blockIdx.x * 256 + threadIdx.x;  // over 256*576 = 147456 (q*576+k)
  int q = i / 576, k = i - q * 576;
  int idx = relidx[i];
  size_t off = ((size_t)(q >> 4) * 36 + (k >> 4)) * 256 + (q & 15) * 16 + (k & 15);
  #pragma unroll
  for (int h = 0; h < 8; h++)
    biasFb[(size_t)h * 147456 + off] =
        __float2bfloat16(ldf(table, (size_t)idx * 8 + h, f) * L2E);
}

// ---------- GEMM: C[m][n] = A[a_off + m][0:256] . BT[n][0:256] + bias[n] ----------
// EPI 0: store to C (d_out, dtype per flag) at c_off, row stride 256   (out proj)
// EPI 1: store bf16 (v*SCALE*log2e), row stride 256                    (q proj)
// EPI 2: ncol<256 -> Kb[m][256] bf16; ncol>=256 -> Vt[w][h][d][n] bf16 (kv proj)
// A dtype: EPI==0 -> always bf16 (internal); else per flag.
template <int EPI>
__global__ __launch_bounds__(256) void gemm_bt(const void* __restrict__ A, size_t a_off,
                                               const bf16* __restrict__ BT,
                                               const void* __restrict__ bias,
                                               void* __restrict__ C, size_t c_off,
                                               bf16* __restrict__ C2,
                                               const int* __restrict__ flagp) {
  __shared__ __align__(16) bf16 As[128 * 40];  // +8 pad kills b128 bank conflicts
  __shared__ __align__(16) bf16 Bs[128 * 40];
  const bool f = (*flagp != 0);
  const bool af = (EPI == 0) ? false : f;  // A dtype (Obuf is internal bf16)
  const int tid = threadIdx.x;
  const int wave = tid >> 6, lane = tid & 63;
  const int q4 = lane >> 4, l16 = lane & 15;
  const int m0 = blockIdx.x * 128, n0 = blockIdx.y * 128;
  const int wm = (wave & 1) * 64, wn = (wave >> 1) * 64;  // 2x2 waves of 64x64
  const int sr = tid >> 2, sc = (tid & 3) * 8;
  floatx4 acc[4][4];
  #pragma unroll
  for (int i = 0; i < 4; i++)
    #pragma unroll
    for (int j = 0; j < 4; j++) acc[i][j] = (floatx4){0.f, 0.f, 0.f, 0.f};

  const size_t abase = a_off + (size_t)(m0 + sr) * 256 + sc;
  const bf16* Bp = BT + (size_t)(n0 + sr) * 256 + sc;
  for (int k0 = 0; k0 < 256; k0 += 32) {
    *(bf16x8*)&As[sr * 40 + sc]        = load8(A, abase + k0, af);
    *(bf16x8*)&As[(sr + 64) * 40 + sc] = load8(A, abase + 64 * 256 + k0, af);
    *(bf16x8*)&Bs[sr * 40 + sc]        = *(const bf16x8*)(Bp + k0);
    *(bf16x8*)&Bs[(sr + 64) * 40 + sc] = *(const bf16x8*)(Bp + 64 * 256 + k0);
    __syncthreads();
    bf16x8 afr[4], bfr[4];
    #pragma unroll
    for (int i = 0; i < 4; i++)
      afr[i] = *(const bf16x8*)&As[(wm + i * 16 + l16) * 40 + q4 * 8];
    #pragma unroll
    for (int j = 0; j < 4; j++)
      bfr[j] = *(const bf16x8*)&Bs[(wn + j * 16 + l16) * 40 + q4 * 8];
    #pragma unroll
    for (int i = 0; i < 4; i++)
      #pragma unroll
      for (int j = 0; j < 4; j++)
        acc[i][j] = MFMA16(afr[i], bfr[j], acc[i][j], 0, 0, 0);
    __syncthreads();
  }
  // epilogue: lane holds rows quad*4+r, col lane&15 of each 16x16 tile
  #pragma unroll
  for (int i = 0; i < 4; i++) {
    #pragma unroll
    for (int j = 0; j < 4; j++) {
      int mrow = m0 + wm + i * 16 + q4 * 4;
      int ncol = n0 + wn + j * 16 + l16;
      float bv = ldf(bias, ncol, f);
      #pragma unroll
      for (int r = 0; r < 4; r++) {
        float v = acc[i][j][r] + bv;
        int m_e = mrow + r;
        if (EPI == 0) {
          size_t oi = c_off + (size_t)m_e * 256 + ncol;
          if (f) ((float*)C)[oi] = v;
          else   ((bf16*)C)[oi] = __float2bfloat16(v);
        } else if (EPI == 1) {
          ((bf16*)C)[(size_t)m_e * 256 + ncol] = __float2bfloat16(v * SCALE_L2E);
        } else {
          if (ncol < 256) {
            ((bf16*)C)[(size_t)m_e * 256 + ncol] = __float2bfloat16(v);
          } else {
            int cc = ncol - 256;
            int hh = cc >> 5, dd = cc & 31;
            int bb = m_e / 576;            // chunk-local window
            int nn = m_e - bb * 576;
            C2[(((size_t)bb * 8 + hh) * 32 + dd) * 576 + nn] = __float2bfloat16(v);
          }
        }
      }
    }
  }
}

// ---------- attention v3: swapped QK^T (k lane-local), defer-max, exp2 domain ----------
// block = (b, h, qc) after XCD swizzle; wave owns 16 q-rows; 9 k-tiles of 64.
// S^T = mfma(K, Q): lane (q4,l16) holds S[kv=16t+4q4+r][q=l16] -> k-reduce is
// in-lane tree + 2 shfls. P staged to LDS as 4x ds_write_b64, read as 2x b128.
// No barriers (per-wave LDS, DS in-order).
__global__ __launch_bounds__(256, 4) void attn(const bf16* __restrict__ Q,     // [W*256][256] *scale*log2e
                                               const bf16* __restrict__ Kb,    // [W*576][256]
                                               const bf16* __restrict__ Vt,    // [W][8][32][576]
                                               const bf16* __restrict__ biasF, // S^T frag layout (*log2e)
                                               bf16* __restrict__ O,           // [W*256][256]
                                               int nwg) {
  __shared__ __align__(16) bf16 P[4][16][72];  // per-wave 16 x 64 (+8 pad): rows 144B, b128-aligned
  __shared__ __align__(16) float SCb[4][16];   // per-wave per-q scale broadcast (rare path + epilogue)
  const int tid = threadIdx.x, wave = tid >> 6, lane = tid & 63;
  const int q4 = lane >> 4, l16 = lane & 15;
  const int cpx = nwg >> 3;                    // nwg % 8 == 0 (W even)
  const int L = (blockIdx.x & 7) * cpx + (blockIdx.x >> 3);
  const int b = L >> 5, h = (L >> 2) & 7, qc = L & 3;
  const int q0 = qc * 64 + wave * 16;
  const int qb = qc * 4 + wave;

  // Q as B-frag: col = l16 (q), k(d) = q4*8+j  (same bytes as the old A-frag load)
  bf16x8 qf = *(const bf16x8*)&Q[((size_t)b * 256 + q0 + l16) * 256 + h * 32 + q4 * 8];
  const bf16* kp = Kb + (size_t)b * 576 * 256 + h * 32 + q4 * 8;          // + kv*256
  const bf16* vp = Vt + ((size_t)b * 8 + h) * 32 * 576 + q4 * 8;          // + d*576 + kv
  const unsigned short* bp =
      (const unsigned short*)biasF + ((size_t)h * 16 + qb) * 9216 + l16 * 16 + q4 * 4;  // + kt*256

  float m = 0.f, l = 0.f;                      // log2-domain running max (per q=l16), denom
  floatx4 o0 = (floatx4){0.f, 0.f, 0.f, 0.f};
  floatx4 o1 = (floatx4){0.f, 0.f, 0.f, 0.f};

  // prefetch tile 0 (K A-frags + bias^T C-frags)
  bf16x8 kf[4]; u16x4 bfr[4];
  #pragma unroll
  for (int t = 0; t < 4; t++) {
    kf[t] = *(const bf16x8*)(kp + (size_t)(16 * t + l16) * 256);
    bfr[t] = *(const u16x4*)(bp + t * 256);
  }

  #pragma unroll 1
  for (int it = 0; it < 9; it++) {
    const int k0 = it * 64;
    // V B-frags (issued early; consumed after softmax)
    bf16x8 vf[2][2];
    #pragma unroll
    for (int ks = 0; ks < 2; ks++) {
      vf[ks][0] = *(const bf16x8*)(vp + (size_t)l16 * 576 + k0 + ks * 32);
      vf[ks][1] = *(const bf16x8*)(vp + (size_t)(l16 + 16) * 576 + k0 + ks * 32);
    }
    // next-tile K/bias prefetch
    bf16x8 kn[4]; u16x4 bn[4];
    if (it < 8) {
      #pragma unroll
      for (int t = 0; t < 4; t++) {
        kn[t] = *(const bf16x8*)(kp + (size_t)(k0 + 64 + 16 * t + l16) * 256);
        bn[t] = *(const u16x4*)(bp + (it + 1) * 1024 + t * 256);
      }
    }
    // S^T = K.Q^T + bias^T : lane holds rows kv=16t+4q4+r, col q=l16 (log2 domain)
    floatx4 s[4];
    __builtin_amdgcn_s_setprio(1);
    #pragma unroll
    for (int t = 0; t < 4; t++) {
      floatx4 c;
      #pragma unroll
      for (int r = 0; r < 4; r++) c[r] = bs2f(bfr[t][r]);
      s[t] = MFMA16(kf[t], qf, c, 0, 0, 0);
    }
    __builtin_amdgcn_s_setprio(0);
    // tile max of this q-row: in-lane tree + 2 cross-quad shfls
    float tm = fmaxf(fmaxf(fmaxf(s[0][0], s[0][1]), fmaxf(s[0][2], s[0][3])),
                     fmaxf(fmaxf(s[1][0], s[1][1]), fmaxf(s[1][2], s[1][3])));
    tm = fmaxf(tm, fmaxf(fmaxf(fmaxf(s[2][0], s[2][1]), fmaxf(s[2][2], s[2][3])),
                         fmaxf(fmaxf(s[3][0], s[3][1]), fmaxf(s[3][2], s[3][3]))));
    tm = fmaxf(tm, __shfl_xor(tm, 16));
    tm = fmaxf(tm, __shfl_xor(tm, 32));
    // speculative exps against current m (independent of the shfl chain)
    float p[4][4];
    #pragma unroll
    for (int t = 0; t < 4; t++)
      #pragma unroll
      for (int r = 0; r < 4; r++)
        p[t][r] = __builtin_amdgcn_exp2f(s[t][r] - m);
    float rs = ((p[0][0] + p[0][1]) + (p[0][2] + p[0][3])) +
               ((p[1][0] + p[1][1]) + (p[1][2] + p[1][3])) +
               ((p[2][0] + p[2][1]) + (p[2][2] + p[2][3])) +
               ((p[3][0] + p[3][1]) + (p[3][2] + p[3][3]));
    if (__any(tm > m + 8.f)) {   // rare: max drifted past defer threshold
      float mn = fmaxf(m, tm);
      float sc = __builtin_amdgcn_exp2f(m - mn);
      #pragma unroll
      for (int t = 0; t < 4; t++)
        #pragma unroll
        for (int r = 0; r < 4; r++) p[t][r] *= sc;
      rs *= sc;
      l *= sc;
      if (q4 == 0) SCb[wave][l16] = sc;
      floatx4 sv = *(const floatx4*)&SCb[wave][q4 * 4];
      #pragma unroll
      for (int r = 0; r < 4; r++) { o0[r] *= sv[r]; o1[r] *= sv[r]; }
      m = mn;
    }
    rs += __shfl_xor(rs, 16);
    rs += __shfl_xor(rs, 32);
    l += rs;
    // P[q=l16][kv-local] staged: kv contiguous per lane -> b64 writes
    #pragma unroll
    for (int t = 0; t < 4; t++) {
      uint2 w;
      w.x = pkbf(p[t][0], p[t][1]);
      w.y = pkbf(p[t][2], p[t][3]);
      *(uint2*)&P[wave][l16][t * 16 + q4 * 4] = w;
    }
    // A-frags for PV: row=l16 (q), k = q4*8+j (kv)
    bf16x8 pf0 = *(const bf16x8*)&P[wave][l16][q4 * 8];
    bf16x8 pf1 = *(const bf16x8*)&P[wave][l16][32 + q4 * 8];
    __builtin_amdgcn_s_setprio(1);
    o0 = MFMA16(pf0, vf[0][0], o0, 0, 0, 0);
    o1 = MFMA16(pf0, vf[0][1], o1, 0, 0, 0);
    o0 = MFMA16(pf1, vf[1][0], o0, 0, 0, 0);
    o1 = MFMA16(pf1, vf[1][1], o1, 0, 0, 0);
    __builtin_amdgcn_s_setprio(0);
    if (it < 8) {
      #pragma unroll
      for (int t = 0; t < 4; t++) { kf[t] = kn[t]; bfr[t] = bn[t]; }
    }
  }
  // normalize: 1/l lives in q=l16 rep; redistribute to O-row rep via LDS broadcast
  float invl = 1.f / l;
  if (q4 == 0) SCb[wave][l16] = invl;
  floatx4 iv = *(const floatx4*)&SCb[wave][q4 * 4];
  bf16* op = O + ((size_t)b * 256 + q0 + q4 * 4) * 256 + h * 32;
  #pragma unroll
  for (int r = 0; r < 4; r++) {
    op[(size_t)r * 256 + l16]      = __float2bfloat16(o0[r] * iv[r]);
    op[(size_t)r * 256 + 16 + l16] = __float2bfloat16(o1[r] * iv[r]);
  }
}

extern "C" void kernel_launch(void* const* d_in, const int* in_sizes, int n_in,
                              void* d_out, int out_size, void* d_ws, size_t ws_size,
                              hipStream_t stream) {
  const void* q_w    = d_in[0];
  const void* kv_w   = d_in[1];
  const void* q_Wm   = d_in[2];
  const void* q_b    = d_in[3];
  const void* kv_Wm  = d_in[4];
  const void* kv_b   = d_in[5];
  const void* proj_Wm= d_in[6];
  const void* proj_b = d_in[7];
  const void* btab   = d_in[8];
  const int*  relidx = (const int*)d_in[9];

  // ---- workspace layout (element offsets are dtype-agnostic) ----
  // flag 256 | WqT 131072 | WkvT 262144 | WpT 131072 | biasFb 2359296 | chunk buffers
  const size_t FIXED = 256 + 131072 + 262144 + 131072 + 2359296;  // 2,883,840
  int W = 2;
  {
    const int cand[8] = {256, 128, 64, 32, 16, 8, 4, 2};
    for (int i = 0; i < 8; i++) {
      if (ws_size >= FIXED + (size_t)cand[i] * 851968ULL) { W = cand[i]; break; }
    }
  }
  const int NCH = 256 / W;

  char* ws = (char*)d_ws;
  int*  flag  = (int*)(ws);
  bf16* WqT   = (bf16*)(ws + 256);
  bf16* WkvT  = (bf16*)(ws + 131328);
  bf16* WpT   = (bf16*)(ws + 393472);
  bf16* biasFb= (bf16*)(ws + 524544);
  char* cb    = ws + FIXED;
  const size_t qsz = (size_t)W * 131072ULL;   // W*256*256*2
  const size_t ksz = (size_t)W * 294912ULL;   // W*576*256*2
  bf16* Qs   = (bf16*)(cb);
  bf16* Kb   = (bf16*)(cb + qsz);
  bf16* Vt   = (bf16*)(cb + qsz + ksz);
  bf16* Obuf = (bf16*)(cb + qsz + 2 * ksz);

  detect_dtype<<<1, 64, 0, stream>>>((const unsigned short*)q_w, flag);
  transpose_w<<<dim3(8, 8),  256, 0, stream>>>(q_Wm,   WqT,  256, flag);
  transpose_w<<<dim3(16, 8), 256, 0, stream>>>(kv_Wm,  WkvT, 512, flag);
  transpose_w<<<dim3(8, 8),  256, 0, stream>>>(proj_Wm,WpT,  256, flag);
  bias_expand<<<576, 256, 0, stream>>>(btab, relidx, biasFb, flag);

  for (int c = 0; c < NCH; c++) {
    const size_t qoff = (size_t)c * W * 65536;    // elements
    const size_t koff = (size_t)c * W * 147456;   // elements
    // q projection (+scale*log2e): M = W*256, N = 256
    gemm_bt<1><<<dim3(2 * W, 2), 256, 0, stream>>>(q_w, qoff, WqT, q_b, Qs, 0, nullptr, flag);
    // kv projection: M = W*576, N = 512 (W even -> grid integral)
    gemm_bt<2><<<dim3((W * 576) / 128, 4), 256, 0, stream>>>(kv_w, koff, WkvT, kv_b, Kb, 0, Vt, flag);
    // attention: W windows * 8 heads * 4 q-chunks
    attn<<<W * 32, 256, 0, stream>>>(Qs, Kb, Vt, biasFb, Obuf, W * 32);
    // output projection: M = W*256, N = 256, store dtype per flag
    gemm_bt<0><<<dim3(2 * W, 2), 256, 0, stream>>>(Obuf, 0, WpT, proj_b, d_out, qoff, nullptr, flag);
  }
}

// Round 3
// 638.172 us; speedup vs baseline: 1.5674x; 1.2686x over previous
//
#include <hip/hip_runtime.h>
#include <hip/hip_bf16.h>

typedef __hip_bfloat16 bf16;
typedef __attribute__((ext_vector_type(8))) short bf16x8;   // 8 bf16 = 4 VGPRs (A/B frag)
typedef __attribute__((ext_vector_type(4))) float floatx4;  // C/D frag
typedef __attribute__((ext_vector_type(4))) unsigned short u16x4;

#define L2E 1.4426950408889634f
#define SCALE_L2E (0.17677669529663687f * 1.4426950408889634f)  // 32^-0.5 * log2(e)
#define MFMA16 __builtin_amdgcn_mfma_f32_16x16x32_bf16

__device__ __forceinline__ short f2bs(float x) {
  union { bf16 h; short s; } u; u.h = __float2bfloat16(x); return u.s;
}
__device__ __forceinline__ float ldf(const void* p, size_t i, bool f32) {
  return f32 ? ((const float*)p)[i] : __bfloat162float(((const bf16*)p)[i]);
}
__device__ __forceinline__ float bs2f(unsigned short u) {
  union { unsigned short u; bf16 h; } v; v.u = u; return __bfloat162float(v.h);
}
__device__ __forceinline__ unsigned int pkbf(float a, float b) {
  union { bf16 h; unsigned short s; } ua, ub;
  ua.h = __float2bfloat16(a); ub.h = __float2bfloat16(b);
  return (unsigned int)ua.s | ((unsigned int)ub.s << 16);
}
// idx is a multiple of 8 at every call site -> float4-aligned
__device__ __forceinline__ bf16x8 load8(const void* p, size_t idx, bool f32) {
  if (f32) {
    const floatx4* fp = (const floatx4*)((const float*)p + idx);
    floatx4 a = fp[0], b = fp[1];
    bf16x8 r;
    r[0] = f2bs(a[0]); r[1] = f2bs(a[1]); r[2] = f2bs(a[2]); r[3] = f2bs(a[3]);
    r[4] = f2bs(b[0]); r[5] = f2bs(b[1]); r[6] = f2bs(b[2]); r[7] = f2bs(b[3]);
    return r;
  }
  return *(const bf16x8*)((const bf16*)p + idx);
}
// bijective XCD-contiguous remap (m204): physical bid round-robins XCDs;
// map so each XCD owns a contiguous logical range.
__device__ __forceinline__ int xcd_remap(int bid, int nwg) {
  int q = nwg >> 3, r = nwg & 7, x = bid & 7, loc = bid >> 3;
  int base = (x < r) ? x * (q + 1) : r * (q + 1) + (x - r) * q;
  return base + loc;
}

// ---------- dtype detector: fp32 data viewed as bf16 words has ~44% huge exponents ----------
__global__ void detect_dtype(const unsigned short* __restrict__ q_w_u16, int* __restrict__ flag) {
  int tid = threadIdx.x;  // 64 threads
  int cnt = 0;
  for (int i = tid; i < 4096; i += 64) {
    int e = (q_w_u16[i] >> 7) & 0xFF;
    cnt += (e >= 145);  // |x| >= 2^18: never for N(0,1) bf16
  }
  #pragma unroll
  for (int off = 32; off; off >>= 1) cnt += __shfl_down(cnt, off);
  if (tid == 0) *flag = (cnt >= 16) ? 1 : 0;
}

// ---------- weight transpose: dst[n][k] = src[k][n], K = 256 rows ----------
__global__ __launch_bounds__(256) void transpose_w(const void* __restrict__ src,
                                                   bf16* __restrict__ dst, int N,
                                                   const int* __restrict__ flagp) {
  __shared__ bf16 t[32][33];
  const bool f = (*flagp != 0);
  int bx = blockIdx.x * 32;  // n base
  int by = blockIdx.y * 32;  // k base
  int x = threadIdx.x & 31, y = threadIdx.x >> 5;
  #pragma unroll
  for (int yy = y; yy < 32; yy += 8)
    t[yy][x] = __float2bfloat16(ldf(src, (size_t)(by + yy) * N + bx + x, f));
  __syncthreads();
  #pragma unroll
  for (int yy = y; yy < 32; yy += 8)
    dst[(size_t)(bx + yy) * 256 + by + x] = t[x][yy];
}

// ---------- bias gather-expand into SWAPPED MFMA-fragment layout (S^T), *log2(e) ----------
// dst[h][qb(16)][kt(36)][ (q&15)(16) ][ (k&15)(16) ] = table[rel[q][k]][h] * log2e
__global__ __launch_bounds__(256) void bias_expand(const void* __restrict__ table,
                                                   const int* __restrict__ relidx,
                                                   bf16* __restrict__ biasFb,
                                                   const int* __restrict__ flagp) {
  const bool f = (*flagp != 0);
  int i = blockIdx.x * 256 + threadIdx.x;  // over 256*576 = 147456 (q*576+k)
  int q = i / 576, k = i - q * 576;
  int idx = relidx[i];
  size_t off = ((size_t)(q >> 4) * 36 + (k >> 4)) * 256 + (q & 15) * 16 + (k & 15);
  #pragma unroll
  for (int h = 0; h < 8; h++)
    biasFb[(size_t)h * 147456 + off] =
        __float2bfloat16(ldf(table, (size_t)idx * 8 + h, f) * L2E);
}

// ---------- GEMM: C[m][n] = A[a_off + m][0:256] . BT[n][0:256] + bias[n] ----------
// 1-D grid; XCD-contiguous remap; n-tile-fastest so consecutive blocks share the A panel in L2.
// EPI 0: store to C (d_out, dtype per flag) at c_off, row stride 256   (out proj)
// EPI 1: store bf16 (v*SCALE*log2e), row stride 256                    (q proj)
// EPI 2: ncol<256 -> Kc[w][h][kv][32]; ncol>=256 -> Vc[w][h][kt][d][kv] (kv proj)
template <int EPI>
__global__ __launch_bounds__(256) void gemm_bt(const void* __restrict__ A, size_t a_off,
                                               const bf16* __restrict__ BT,
                                               const void* __restrict__ bias,
                                               void* __restrict__ C, size_t c_off,
                                               bf16* __restrict__ C2,
                                               const int* __restrict__ flagp) {
  __shared__ __align__(16) bf16 As[128 * 40];  // +8 pad kills b128 bank conflicts
  __shared__ __align__(16) bf16 Bs[128 * 40];
  const bool f = (*flagp != 0);
  const bool af = (EPI == 0) ? false : f;  // A dtype (Obuf is internal bf16)
  const int tid = threadIdx.x;
  const int wave = tid >> 6, lane = tid & 63;
  const int q4 = lane >> 4, l16 = lane & 15;
  constexpr int NT = (EPI == 2) ? 4 : 2;      // n-tiles
  constexpr int LNT = (EPI == 2) ? 2 : 1;
  const int L = xcd_remap(blockIdx.x, gridDim.x);
  const int m0 = (L >> LNT) * 128, n0 = (L & (NT - 1)) * 128;
  const int wm = (wave & 1) * 64, wn = (wave >> 1) * 64;  // 2x2 waves of 64x64
  const int sr = tid >> 2, sc = (tid & 3) * 8;
  floatx4 acc[4][4];
  #pragma unroll
  for (int i = 0; i < 4; i++)
    #pragma unroll
    for (int j = 0; j < 4; j++) acc[i][j] = (floatx4){0.f, 0.f, 0.f, 0.f};

  const size_t abase = a_off + (size_t)(m0 + sr) * 256 + sc;
  const bf16* Bp = BT + (size_t)(n0 + sr) * 256 + sc;
  for (int k0 = 0; k0 < 256; k0 += 32) {
    *(bf16x8*)&As[sr * 40 + sc]        = load8(A, abase + k0, af);
    *(bf16x8*)&As[(sr + 64) * 40 + sc] = load8(A, abase + 64 * 256 + k0, af);
    *(bf16x8*)&Bs[sr * 40 + sc]        = *(const bf16x8*)(Bp + k0);
    *(bf16x8*)&Bs[(sr + 64) * 40 + sc] = *(const bf16x8*)(Bp + 64 * 256 + k0);
    __syncthreads();
    bf16x8 afr[4], bfr[4];
    #pragma unroll
    for (int i = 0; i < 4; i++)
      afr[i] = *(const bf16x8*)&As[(wm + i * 16 + l16) * 40 + q4 * 8];
    #pragma unroll
    for (int j = 0; j < 4; j++)
      bfr[j] = *(const bf16x8*)&Bs[(wn + j * 16 + l16) * 40 + q4 * 8];
    #pragma unroll
    for (int i = 0; i < 4; i++)
      #pragma unroll
      for (int j = 0; j < 4; j++)
        acc[i][j] = MFMA16(afr[i], bfr[j], acc[i][j], 0, 0, 0);
    __syncthreads();
  }
  // epilogue: lane holds rows quad*4+r, col lane&15 of each 16x16 tile
  #pragma unroll
  for (int i = 0; i < 4; i++) {
    #pragma unroll
    for (int j = 0; j < 4; j++) {
      int mrow = m0 + wm + i * 16 + q4 * 4;
      int ncol = n0 + wn + j * 16 + l16;
      float bv = ldf(bias, ncol, f);
      #pragma unroll
      for (int r = 0; r < 4; r++) {
        float v = acc[i][j][r] + bv;
        int m_e = mrow + r;
        if (EPI == 0) {
          size_t oi = c_off + (size_t)m_e * 256 + ncol;
          if (f) ((float*)C)[oi] = v;
          else   ((bf16*)C)[oi] = __float2bfloat16(v);
        } else if (EPI == 1) {
          ((bf16*)C)[(size_t)m_e * 256 + ncol] = __float2bfloat16(v * SCALE_L2E);
        } else {
          int bb = m_e / 576;              // chunk-local window
          int nn = m_e - bb * 576;         // kv index
          if (ncol < 256) {
            int hh = ncol >> 5, dd = ncol & 31;
            // K: [w][h][kv 576][d 32]
            ((bf16*)C)[(((size_t)bb * 8 + hh) * 576 + nn) * 32 + dd] = __float2bfloat16(v);
          } else {
            int cc = ncol - 256;
            int hh = cc >> 5, dd = cc & 31;
            int kt = nn >> 6, kvl = nn & 63;
            // V: [w][h][kt 9][d 32][kv 64]
            C2[((((size_t)bb * 8 + hh) * 9 + kt) * 32 + dd) * 64 + kvl] = __float2bfloat16(v);
          }
        }
      }
    }
  }
}

// ---------- attention v4: LDS-staged K/V tiles (coalesced, 4x less VM), raw-barrier pipeline ----------
// block = (b, h, qc); wave owns 16 q-rows; 9 k-tiles of 64 kv.
// K/V staged cooperatively (double-buffered, XOR-chunk swizzle); bias direct (contiguous);
// one s_barrier per iter, lgkmcnt(0) only -> next-tile global loads stay in flight.
__global__ __launch_bounds__(256, 4) void attn(const bf16* __restrict__ Q,     // [W*256][256] *scale*log2e
                                               const bf16* __restrict__ Kc,    // [W][8][576][32]
                                               const bf16* __restrict__ Vc,    // [W][8][9][32][64]
                                               const bf16* __restrict__ biasF, // S^T frag layout (*log2e)
                                               bf16* __restrict__ O,           // [W*256][256]
                                               int nwg) {
  __shared__ __align__(16) bf16 Ks[2][64][32];  // 8 KB, chunk-swizzled
  __shared__ __align__(16) bf16 Vs[2][32][64];  // 8 KB, chunk-swizzled
  __shared__ __align__(16) bf16 P[4][16][72];   // 9 KB per-wave P (rows 144 B, 16B-aligned)
  __shared__ float SCb[4][16];
  const int tid = threadIdx.x, wave = tid >> 6, lane = tid & 63;
  const int q4 = lane >> 4, l16 = lane & 15;
  const int L = xcd_remap(blockIdx.x, nwg);
  const int b = L >> 5, h = (L >> 2) & 7, qc = L & 3;
  const int q0 = qc * 64 + wave * 16;
  const int qb = qc * 4 + wave;

  // Q as B-frag: col = l16 (q), k(d) = q4*8+j
  bf16x8 qf = *(const bf16x8*)&Q[((size_t)b * 256 + q0 + l16) * 256 + h * 32 + q4 * 8];
  const bf16* kg = Kc + ((size_t)b * 8 + h) * 18432;  // + it*2048 + tid*8 (tile contiguous)
  const bf16* vg = Vc + ((size_t)b * 8 + h) * 18432;
  const unsigned short* bp =
      (const unsigned short*)biasF + ((size_t)h * 16 + qb) * 9216 + l16 * 16 + q4 * 4;  // + kt*256

  // staging destinations (XOR chunk swizzle: orig chunk c of row r lives at c ^ (r & (nc-1)))
  bf16* ksd = &Ks[0][tid >> 2][(((tid & 3) ^ ((tid >> 2) & 3))) * 8];
  bf16* vsd = &Vs[0][tid >> 3][(((tid & 7) ^ ((tid >> 3) & 7))) * 8];
  const int kx = (l16 & 3);   // K read swizzle key (row & 3)
  const int vx = (l16 & 7);   // V read swizzle key (row & 7)

  float m = 0.f, l = 0.f;
  floatx4 o0 = (floatx4){0.f, 0.f, 0.f, 0.f};
  floatx4 o1 = (floatx4){0.f, 0.f, 0.f, 0.f};

  // prologue: stage tile 0, prefetch bias tile 0
  {
    bf16x8 k0r = *(const bf16x8*)(kg + tid * 8);
    bf16x8 v0r = *(const bf16x8*)(vg + tid * 8);
    *(bf16x8*)ksd = k0r;
    *(bf16x8*)vsd = v0r;
  }
  u16x4 bfr[4];
  #pragma unroll
  for (int t = 0; t < 4; t++) bfr[t] = *(const u16x4*)(bp + t * 256);
  asm volatile("s_waitcnt lgkmcnt(0)" ::: "memory");
  __builtin_amdgcn_sched_barrier(0);
  __builtin_amdgcn_s_barrier();
  __builtin_amdgcn_sched_barrier(0);

  #pragma unroll 1
  for (int it = 0; it < 9; it++) {
    const int cur = it & 1;
    const int nx = (cur ^ 1) * 2048;
    // issue next-tile global loads first (land during this iter's compute)
    bf16x8 kNr, vNr; u16x4 bn[4];
    if (it < 8) {
      kNr = *(const bf16x8*)(kg + (it + 1) * 2048 + tid * 8);
      vNr = *(const bf16x8*)(vg + (it + 1) * 2048 + tid * 8);
      #pragma unroll
      for (int t = 0; t < 4; t++) bn[t] = *(const u16x4*)(bp + (it + 1) * 1024 + t * 256);
    }
    // S^T = K.Q^T + bias^T (K frags from LDS): lane holds kv=16t+4q4+r, q=l16
    floatx4 s[4];
    __builtin_amdgcn_s_setprio(1);
    #pragma unroll
    for (int t = 0; t < 4; t++) {
      bf16x8 kf = *(const bf16x8*)&Ks[cur][t * 16 + l16][(q4 ^ kx) * 8];
      floatx4 c;
      #pragma unroll
      for (int r = 0; r < 4; r++) c[r] = bs2f(bfr[t][r]);
      s[t] = MFMA16(kf, qf, c, 0, 0, 0);
    }
    __builtin_amdgcn_s_setprio(0);
    // tile max of this q-row: in-lane tree + 2 cross-half shfls
    float tm = fmaxf(fmaxf(fmaxf(s[0][0], s[0][1]), fmaxf(s[0][2], s[0][3])),
                     fmaxf(fmaxf(s[1][0], s[1][1]), fmaxf(s[1][2], s[1][3])));
    tm = fmaxf(tm, fmaxf(fmaxf(fmaxf(s[2][0], s[2][1]), fmaxf(s[2][2], s[2][3])),
                         fmaxf(fmaxf(s[3][0], s[3][1]), fmaxf(s[3][2], s[3][3]))));
    tm = fmaxf(tm, __shfl_xor(tm, 16));
    tm = fmaxf(tm, __shfl_xor(tm, 32));
    // speculative exps against current m (defer-max)
    float p[4][4];
    #pragma unroll
    for (int t = 0; t < 4; t++)
      #pragma unroll
      for (int r = 0; r < 4; r++)
        p[t][r] = __builtin_amdgcn_exp2f(s[t][r] - m);
    float rs = ((p[0][0] + p[0][1]) + (p[0][2] + p[0][3])) +
               ((p[1][0] + p[1][1]) + (p[1][2] + p[1][3])) +
               ((p[2][0] + p[2][1]) + (p[2][2] + p[2][3])) +
               ((p[3][0] + p[3][1]) + (p[3][2] + p[3][3]));
    if (__any(tm > m + 8.f)) {   // rare: max drifted past defer threshold
      float mn = fmaxf(m, tm);
      float sc = __builtin_amdgcn_exp2f(m - mn);
      #pragma unroll
      for (int t = 0; t < 4; t++)
        #pragma unroll
        for (int r = 0; r < 4; r++) p[t][r] *= sc;
      rs *= sc;
      l *= sc;
      if (q4 == 0) SCb[wave][l16] = sc;
      floatx4 sv = *(const floatx4*)&SCb[wave][q4 * 4];
      #pragma unroll
      for (int r = 0; r < 4; r++) { o0[r] *= sv[r]; o1[r] *= sv[r]; }
      m = mn;
    }
    rs += __shfl_xor(rs, 16);
    rs += __shfl_xor(rs, 32);
    l += rs;
    // P stage: kv contiguous per lane -> b64 writes (per-wave buffer, no barrier needed)
    #pragma unroll
    for (int t = 0; t < 4; t++) {
      uint2 w;
      w.x = pkbf(p[t][0], p[t][1]);
      w.y = pkbf(p[t][2], p[t][3]);
      *(uint2*)&P[wave][l16][t * 16 + q4 * 4] = w;
    }
    bf16x8 pf0 = *(const bf16x8*)&P[wave][l16][q4 * 8];
    bf16x8 pf1 = *(const bf16x8*)&P[wave][l16][32 + q4 * 8];
    // V frags from LDS: row d = l16(+16), orig kv-chunk ks*4+q4 at position ^(row&7)
    bf16x8 v00 = *(const bf16x8*)&Vs[cur][l16][((q4 ^ vx)) * 8];
    bf16x8 v01 = *(const bf16x8*)&Vs[cur][l16 + 16][((q4 ^ vx)) * 8];
    bf16x8 v10 = *(const bf16x8*)&Vs[cur][l16][(((4 + q4) ^ vx)) * 8];
    bf16x8 v11 = *(const bf16x8*)&Vs[cur][l16 + 16][(((4 + q4) ^ vx)) * 8];
    __builtin_amdgcn_s_setprio(1);
    o0 = MFMA16(pf0, v00, o0, 0, 0, 0);
    o1 = MFMA16(pf0, v01, o1, 0, 0, 0);
    o0 = MFMA16(pf1, v10, o0, 0, 0, 0);
    o1 = MFMA16(pf1, v11, o1, 0, 0, 0);
    __builtin_amdgcn_s_setprio(0);
    // stage next tile into the other buffer; bias rotate
    if (it < 8) {
      *(bf16x8*)(ksd + nx) = kNr;
      *(bf16x8*)(vsd + nx) = vNr;
      #pragma unroll
      for (int t = 0; t < 4; t++) bfr[t] = bn[t];
    }
    asm volatile("s_waitcnt lgkmcnt(0)" ::: "memory");
    __builtin_amdgcn_sched_barrier(0);
    __builtin_amdgcn_s_barrier();
    __builtin_amdgcn_sched_barrier(0);
  }
  // normalize: 1/l lives in q=l16 rep; redistribute to O-row rep via per-wave LDS broadcast
  float invl = 1.f / l;
  if (q4 == 0) SCb[wave][l16] = invl;
  floatx4 iv = *(const floatx4*)&SCb[wave][q4 * 4];
  bf16* op = O + ((size_t)b * 256 + q0 + q4 * 4) * 256 + h * 32;
  #pragma unroll
  for (int r = 0; r < 4; r++) {
    op[(size_t)r * 256 + l16]      = __float2bfloat16(o0[r] * iv[r]);
    op[(size_t)r * 256 + 16 + l16] = __float2bfloat16(o1[r] * iv[r]);
  }
}

extern "C" void kernel_launch(void* const* d_in, const int* in_sizes, int n_in,
                              void* d_out, int out_size, void* d_ws, size_t ws_size,
                              hipStream_t stream) {
  const void* q_w    = d_in[0];
  const void* kv_w   = d_in[1];
  const void* q_Wm   = d_in[2];
  const void* q_b    = d_in[3];
  const void* kv_Wm  = d_in[4];
  const void* kv_b   = d_in[5];
  const void* proj_Wm= d_in[6];
  const void* proj_b = d_in[7];
  const void* btab   = d_in[8];
  const int*  relidx = (const int*)d_in[9];

  // ---- workspace layout (element offsets are dtype-agnostic) ----
  // flag 256 | WqT 131072 | WkvT 262144 | WpT 131072 | biasFb 2359296 | chunk buffers
  const size_t FIXED = 256 + 131072 + 262144 + 131072 + 2359296;  // 2,883,840
  int W = 2;
  {
    const int cand[8] = {256, 128, 64, 32, 16, 8, 4, 2};
    for (int i = 0; i < 8; i++) {
      if (ws_size >= FIXED + (size_t)cand[i] * 851968ULL) { W = cand[i]; break; }
    }
  }
  const int NCH = 256 / W;

  char* ws = (char*)d_ws;
  int*  flag  = (int*)(ws);
  bf16* WqT   = (bf16*)(ws + 256);
  bf16* WkvT  = (bf16*)(ws + 131328);
  bf16* WpT   = (bf16*)(ws + 393472);
  bf16* biasFb= (bf16*)(ws + 524544);
  char* cb    = ws + FIXED;
  const size_t qsz = (size_t)W * 131072ULL;   // W*256*256*2
  const size_t ksz = (size_t)W * 294912ULL;   // W*576*256*2
  bf16* Qs   = (bf16*)(cb);
  bf16* Kb   = (bf16*)(cb + qsz);
  bf16* Vt   = (bf16*)(cb + qsz + ksz);
  bf16* Obuf = (bf16*)(cb + qsz + 2 * ksz);

  detect_dtype<<<1, 64, 0, stream>>>((const unsigned short*)q_w, flag);
  transpose_w<<<dim3(8, 8),  256, 0, stream>>>(q_Wm,   WqT,  256, flag);
  transpose_w<<<dim3(16, 8), 256, 0, stream>>>(kv_Wm,  WkvT, 512, flag);
  transpose_w<<<dim3(8, 8),  256, 0, stream>>>(proj_Wm,WpT,  256, flag);
  bias_expand<<<576, 256, 0, stream>>>(btab, relidx, biasFb, flag);

  for (int c = 0; c < NCH; c++) {
    const size_t qoff = (size_t)c * W * 65536;    // elements
    const size_t koff = (size_t)c * W * 147456;   // elements
    // q projection (+scale*log2e): M = W*256, N = 256 -> 1-D grid, n-fastest
    gemm_bt<1><<<4 * W, 256, 0, stream>>>(q_w, qoff, WqT, q_b, Qs, 0, nullptr, flag);
    // kv projection: M = W*576, N = 512 -> nwg = 18W
    gemm_bt<2><<<18 * W, 256, 0, stream>>>(kv_w, koff, WkvT, kv_b, Kb, 0, Vt, flag);
    // attention: W windows * 8 heads * 4 q-chunks
    attn<<<W * 32, 256, 0, stream>>>(Qs, Kb, Vt, biasFb, Obuf, W * 32);
    // output projection: M = W*256, N = 256, store dtype per flag
    gemm_bt<0><<<4 * W, 256, 0, stream>>>(Obuf, 0, WpT, proj_b, d_out, qoff, nullptr, flag);
  }
}

// Round 4
// 559.256 us; speedup vs baseline: 1.7885x; 1.1411x over previous
//
#include <hip/hip_runtime.h>
#include <hip/hip_bf16.h>

typedef __hip_bfloat16 bf16;
typedef __attribute__((ext_vector_type(8))) short bf16x8;   // 8 bf16 = 4 VGPRs (A/B frag)
typedef __attribute__((ext_vector_type(4))) float floatx4;  // C/D frag
typedef __attribute__((ext_vector_type(4))) unsigned short u16x4;

#define L2E 1.4426950408889634f
#define SCALE_L2E (0.17677669529663687f * 1.4426950408889634f)  // 32^-0.5 * log2(e)
#define MFMA16 __builtin_amdgcn_mfma_f32_16x16x32_bf16

__device__ __forceinline__ short f2bs(float x) {
  union { bf16 h; short s; } u; u.h = __float2bfloat16(x); return u.s;
}
__device__ __forceinline__ float ldf(const void* p, size_t i, bool f32) {
  return f32 ? ((const float*)p)[i] : __bfloat162float(((const bf16*)p)[i]);
}
__device__ __forceinline__ float bs2f(unsigned short u) {
  union { unsigned short u; bf16 h; } v; v.u = u; return __bfloat162float(v.h);
}
__device__ __forceinline__ unsigned int pkbf(float a, float b) {
  union { bf16 h; unsigned short s; } ua, ub;
  ua.h = __float2bfloat16(a); ub.h = __float2bfloat16(b);
  return (unsigned int)ua.s | ((unsigned int)ub.s << 16);
}
// raw A prefetch holder: f32 path uses x+y (2 float4), bf16 path uses x only (16B raw)
struct APre { floatx4 x, y; };
__device__ __forceinline__ APre loadA(const void* p, size_t idx, bool f32) {
  APre r;
  if (f32) {
    const floatx4* fp = (const floatx4*)((const float*)p + idx);
    r.x = fp[0]; r.y = fp[1];
  } else {
    r.x = *(const floatx4*)((const bf16*)p + idx);
    r.y = r.x;
  }
  return r;
}
__device__ __forceinline__ bf16x8 cvtA(const APre& a, bool f32) {
  if (f32) {
    bf16x8 r;
    r[0] = f2bs(a.x[0]); r[1] = f2bs(a.x[1]); r[2] = f2bs(a.x[2]); r[3] = f2bs(a.x[3]);
    r[4] = f2bs(a.y[0]); r[5] = f2bs(a.y[1]); r[6] = f2bs(a.y[2]); r[7] = f2bs(a.y[3]);
    return r;
  }
  union { floatx4 f; bf16x8 h; } u; u.f = a.x; return u.h;
}
// bijective XCD-contiguous remap (m204): physical bid round-robins XCDs;
// map so each XCD owns a contiguous logical range.
__device__ __forceinline__ int xcd_remap(int bid, int nwg) {
  int q = nwg >> 3, r = nwg & 7, x = bid & 7, loc = bid >> 3;
  int base = (x < r) ? x * (q + 1) : r * (q + 1) + (x - r) * q;
  return base + loc;
}

// ---------- dtype detector: fp32 data viewed as bf16 words has ~44% huge exponents ----------
__global__ void detect_dtype(const unsigned short* __restrict__ q_w_u16, int* __restrict__ flag) {
  int tid = threadIdx.x;  // 64 threads
  int cnt = 0;
  for (int i = tid; i < 4096; i += 64) {
    int e = (q_w_u16[i] >> 7) & 0xFF;
    cnt += (e >= 145);  // |x| >= 2^18: never for N(0,1) bf16
  }
  #pragma unroll
  for (int off = 32; off; off >>= 1) cnt += __shfl_down(cnt, off);
  if (tid == 0) *flag = (cnt >= 16) ? 1 : 0;
}

// ---------- weight transpose: dst[n][k] = src[k][n], K = 256 rows ----------
__global__ __launch_bounds__(256) void transpose_w(const void* __restrict__ src,
                                                   bf16* __restrict__ dst, int N,
                                                   const int* __restrict__ flagp) {
  __shared__ bf16 t[32][33];
  const bool f = (*flagp != 0);
  int bx = blockIdx.x * 32;  // n base
  int by = blockIdx.y * 32;  // k base
  int x = threadIdx.x & 31, y = threadIdx.x >> 5;
  #pragma unroll
  for (int yy = y; yy < 32; yy += 8)
    t[yy][x] = __float2bfloat16(ldf(src, (size_t)(by + yy) * N + bx + x, f));
  __syncthreads();
  #pragma unroll
  for (int yy = y; yy < 32; yy += 8)
    dst[(size_t)(bx + yy) * 256 + by + x] = t[x][yy];
}

// ---------- bias gather-expand into SWAPPED MFMA-fragment layout (S^T), *log2(e) ----------
// dst[h][qb(16)][kt(36)][ (q&15)(16) ][ (k&15)(16) ] = table[rel[q][k]][h] * log2e
__global__ __launch_bounds__(256) void bias_expand(const void* __restrict__ table,
                                                   const int* __restrict__ relidx,
                                                   bf16* __restrict__ biasFb,
                                                   const int* __restrict__ flagp) {
  const bool f = (*flagp != 0);
  int i = blockIdx.x * 256 + threadIdx.x;  // over 256*576 = 147456 (q*576+k)
  int q = i / 576, k = i - q * 576;
  int idx = relidx[i];
  size_t off = ((size_t)(q >> 4) * 36 + (k >> 4)) * 256 + (q & 15) * 16 + (k & 15);
  #pragma unroll
  for (int h = 0; h < 8; h++)
    biasFb[(size_t)h * 147456 + off] =
        __float2bfloat16(ldf(table, (size_t)idx * 8 + h, f) * L2E);
}

// ---------- GEMM: C[m][n] = A[a_off + m][0:256] . BT[n][0:256] + bias[n] ----------
// Software-pipelined: register-prefetch next k-step before MFMA, LDS double-buffer,
// ONE barrier per k-step. 1-D grid, XCD-contiguous remap, n-tile-fastest (A-panel L2 reuse).
// EPI 0: store to C (d_out, dtype per flag) at c_off, row stride 256   (out proj)
// EPI 1: store bf16 (v*SCALE*log2e), row stride 256                    (q proj)
// EPI 2: ncol<256 -> Kc[w][h][kv][32]; ncol>=256 -> Vc[w][h][kt][d][kv] (kv proj)
template <int EPI>
__global__ __launch_bounds__(256) void gemm_bt(const void* __restrict__ A, size_t a_off,
                                               const bf16* __restrict__ BT,
                                               const void* __restrict__ bias,
                                               void* __restrict__ C, size_t c_off,
                                               bf16* __restrict__ C2,
                                               const int* __restrict__ flagp) {
  __shared__ __align__(16) bf16 As[2][128 * 40];  // dbuf; +8 pad kills b128 bank conflicts
  __shared__ __align__(16) bf16 Bs[2][128 * 40];
  const bool f = (*flagp != 0);
  const bool af = (EPI == 0) ? false : f;  // A dtype (Obuf is internal bf16)
  const int tid = threadIdx.x;
  const int wave = tid >> 6, lane = tid & 63;
  const int q4 = lane >> 4, l16 = lane & 15;
  constexpr int NT = (EPI == 2) ? 4 : 2;      // n-tiles
  constexpr int LNT = (EPI == 2) ? 2 : 1;
  const int L = xcd_remap(blockIdx.x, gridDim.x);
  const int m0 = (L >> LNT) * 128, n0 = (L & (NT - 1)) * 128;
  const int wm = (wave & 1) * 64, wn = (wave >> 1) * 64;  // 2x2 waves of 64x64
  const int sr = tid >> 2, sc = (tid & 3) * 8;
  floatx4 acc[4][4];
  #pragma unroll
  for (int i = 0; i < 4; i++)
    #pragma unroll
    for (int j = 0; j < 4; j++) acc[i][j] = (floatx4){0.f, 0.f, 0.f, 0.f};

  const size_t abase = a_off + (size_t)(m0 + sr) * 256 + sc;
  const bf16* Bp = BT + (size_t)(n0 + sr) * 256 + sc;

  // prologue: load + stage k-step 0 into buf 0
  {
    APre a0 = loadA(A, abase, af);
    APre a1 = loadA(A, abase + 64 * 256, af);
    bf16x8 b0 = *(const bf16x8*)(Bp);
    bf16x8 b1 = *(const bf16x8*)(Bp + 64 * 256);
    *(bf16x8*)&As[0][sr * 40 + sc]        = cvtA(a0, af);
    *(bf16x8*)&As[0][(sr + 64) * 40 + sc] = cvtA(a1, af);
    *(bf16x8*)&Bs[0][sr * 40 + sc]        = b0;
    *(bf16x8*)&Bs[0][(sr + 64) * 40 + sc] = b1;
  }
  __syncthreads();

  #pragma unroll
  for (int t = 0; t < 8; t++) {
    const int cur = t & 1, nxt = cur ^ 1;
    // issue next k-step's global loads FIRST; their waitcnt lands after the MFMAs
    APre na0, na1; bf16x8 nb0, nb1;
    if (t < 7) {
      na0 = loadA(A, abase + (t + 1) * 32, af);
      na1 = loadA(A, abase + 64 * 256 + (t + 1) * 32, af);
      nb0 = *(const bf16x8*)(Bp + (t + 1) * 32);
      nb1 = *(const bf16x8*)(Bp + 64 * 256 + (t + 1) * 32);
    }
    bf16x8 afr[4], bfr[4];
    #pragma unroll
    for (int i = 0; i < 4; i++)
      afr[i] = *(const bf16x8*)&As[cur][(wm + i * 16 + l16) * 40 + q4 * 8];
    #pragma unroll
    for (int j = 0; j < 4; j++)
      bfr[j] = *(const bf16x8*)&Bs[cur][(wn + j * 16 + l16) * 40 + q4 * 8];
    #pragma unroll
    for (int i = 0; i < 4; i++)
      #pragma unroll
      for (int j = 0; j < 4; j++)
        acc[i][j] = MFMA16(afr[i], bfr[j], acc[i][j], 0, 0, 0);
    if (t < 7) {
      // stage next tile into the other buffer (vmcnt wait happens here, post-MFMA)
      *(bf16x8*)&As[nxt][sr * 40 + sc]        = cvtA(na0, af);
      *(bf16x8*)&As[nxt][(sr + 64) * 40 + sc] = cvtA(na1, af);
      *(bf16x8*)&Bs[nxt][sr * 40 + sc]        = nb0;
      *(bf16x8*)&Bs[nxt][(sr + 64) * 40 + sc] = nb1;
      __syncthreads();  // single barrier per k-step: publishes nxt, guards cur reuse
    }
  }

  // epilogue: lane holds rows quad*4+r, col lane&15 of each 16x16 tile
  #pragma unroll
  for (int i = 0; i < 4; i++) {
    #pragma unroll
    for (int j = 0; j < 4; j++) {
      int mrow = m0 + wm + i * 16 + q4 * 4;
      int ncol = n0 + wn + j * 16 + l16;
      float bv = ldf(bias, ncol, f);
      if (EPI == 2 && ncol >= 256) {
        // V: [w][h][kt 9][d 32][kv 64] — r-values are kv-consecutive -> one 8B store
        int cc = ncol - 256, hh = cc >> 5, dd = cc & 31;
        int bb = mrow / 576, nn = mrow - bb * 576;   // nn%4==0, never crosses 64/576 bounds
        u16x4 w;
        #pragma unroll
        for (int r = 0; r < 4; r++) {
          union { bf16 h; unsigned short s; } u;
          u.h = __float2bfloat16(acc[i][j][r] + bv);
          w[r] = u.s;
        }
        *(u16x4*)&C2[((((size_t)bb * 8 + hh) * 9 + (nn >> 6)) * 32 + dd) * 64 + (nn & 63)] = w;
      } else {
        #pragma unroll
        for (int r = 0; r < 4; r++) {
          float v = acc[i][j][r] + bv;
          int m_e = mrow + r;
          if (EPI == 0) {
            size_t oi = c_off + (size_t)m_e * 256 + ncol;
            if (f) ((float*)C)[oi] = v;
            else   ((bf16*)C)[oi] = __float2bfloat16(v);
          } else if (EPI == 1) {
            ((bf16*)C)[(size_t)m_e * 256 + ncol] = __float2bfloat16(v * SCALE_L2E);
          } else {
            // K: [w][h][kv 576][d 32]
            int bb = m_e / 576, nn = m_e - bb * 576;
            int hh = ncol >> 5, dd = ncol & 31;
            ((bf16*)C)[(((size_t)bb * 8 + hh) * 576 + nn) * 32 + dd] = __float2bfloat16(v);
          }
        }
      }
    }
  }
}

// ---------- attention v4: LDS-staged K/V tiles (coalesced, 4x less VM), raw-barrier pipeline ----------
// block = (b, h, qc); wave owns 16 q-rows; 9 k-tiles of 64 kv.
// K/V staged cooperatively (double-buffered, XOR-chunk swizzle); bias direct (contiguous);
// one s_barrier per iter, lgkmcnt(0) only -> next-tile global loads stay in flight.
__global__ __launch_bounds__(256, 4) void attn(const bf16* __restrict__ Q,     // [W*256][256] *scale*log2e
                                               const bf16* __restrict__ Kc,    // [W][8][576][32]
                                               const bf16* __restrict__ Vc,    // [W][8][9][32][64]
                                               const bf16* __restrict__ biasF, // S^T frag layout (*log2e)
                                               bf16* __restrict__ O,           // [W*256][256]
                                               int nwg) {
  __shared__ __align__(16) bf16 Ks[2][64][32];  // 8 KB, chunk-swizzled
  __shared__ __align__(16) bf16 Vs[2][32][64];  // 8 KB, chunk-swizzled
  __shared__ __align__(16) bf16 P[4][16][72];   // 9 KB per-wave P (rows 144 B, 16B-aligned)
  __shared__ float SCb[4][16];
  const int tid = threadIdx.x, wave = tid >> 6, lane = tid & 63;
  const int q4 = lane >> 4, l16 = lane & 15;
  const int L = xcd_remap(blockIdx.x, nwg);
  const int b = L >> 5, h = (L >> 2) & 7, qc = L & 3;
  const int q0 = qc * 64 + wave * 16;
  const int qb = qc * 4 + wave;

  // Q as B-frag: col = l16 (q), k(d) = q4*8+j
  bf16x8 qf = *(const bf16x8*)&Q[((size_t)b * 256 + q0 + l16) * 256 + h * 32 + q4 * 8];
  const bf16* kg = Kc + ((size_t)b * 8 + h) * 18432;  // + it*2048 + tid*8 (tile contiguous)
  const bf16* vg = Vc + ((size_t)b * 8 + h) * 18432;
  const unsigned short* bp =
      (const unsigned short*)biasF + ((size_t)h * 16 + qb) * 9216 + l16 * 16 + q4 * 4;  // + kt*256

  // staging destinations (XOR chunk swizzle: orig chunk c of row r lives at c ^ (r & (nc-1)))
  bf16* ksd = &Ks[0][tid >> 2][(((tid & 3) ^ ((tid >> 2) & 3))) * 8];
  bf16* vsd = &Vs[0][tid >> 3][(((tid & 7) ^ ((tid >> 3) & 7))) * 8];
  const int kx = (l16 & 3);   // K read swizzle key (row & 3)
  const int vx = (l16 & 7);   // V read swizzle key (row & 7)

  float m = 0.f, l = 0.f;
  floatx4 o0 = (floatx4){0.f, 0.f, 0.f, 0.f};
  floatx4 o1 = (floatx4){0.f, 0.f, 0.f, 0.f};

  // prologue: stage tile 0, prefetch bias tile 0
  {
    bf16x8 k0r = *(const bf16x8*)(kg + tid * 8);
    bf16x8 v0r = *(const bf16x8*)(vg + tid * 8);
    *(bf16x8*)ksd = k0r;
    *(bf16x8*)vsd = v0r;
  }
  u16x4 bfr[4];
  #pragma unroll
  for (int t = 0; t < 4; t++) bfr[t] = *(const u16x4*)(bp + t * 256);
  asm volatile("s_waitcnt lgkmcnt(0)" ::: "memory");
  __builtin_amdgcn_sched_barrier(0);
  __builtin_amdgcn_s_barrier();
  __builtin_amdgcn_sched_barrier(0);

  #pragma unroll 1
  for (int it = 0; it < 9; it++) {
    const int cur = it & 1;
    const int nx = (cur ^ 1) * 2048;
    // issue next-tile global loads first (land during this iter's compute)
    bf16x8 kNr, vNr; u16x4 bn[4];
    if (it < 8) {
      kNr = *(const bf16x8*)(kg + (it + 1) * 2048 + tid * 8);
      vNr = *(const bf16x8*)(vg + (it + 1) * 2048 + tid * 8);
      #pragma unroll
      for (int t = 0; t < 4; t++) bn[t] = *(const u16x4*)(bp + (it + 1) * 1024 + t * 256);
    }
    // S^T = K.Q^T + bias^T (K frags from LDS): lane holds kv=16t+4q4+r, q=l16
    floatx4 s[4];
    __builtin_amdgcn_s_setprio(1);
    #pragma unroll
    for (int t = 0; t < 4; t++) {
      bf16x8 kf = *(const bf16x8*)&Ks[cur][t * 16 + l16][(q4 ^ kx) * 8];
      floatx4 c;
      #pragma unroll
      for (int r = 0; r < 4; r++) c[r] = bs2f(bfr[t][r]);
      s[t] = MFMA16(kf, qf, c, 0, 0, 0);
    }
    __builtin_amdgcn_s_setprio(0);
    // tile max of this q-row: in-lane tree + 2 cross-half shfls
    float tm = fmaxf(fmaxf(fmaxf(s[0][0], s[0][1]), fmaxf(s[0][2], s[0][3])),
                     fmaxf(fmaxf(s[1][0], s[1][1]), fmaxf(s[1][2], s[1][3])));
    tm = fmaxf(tm, fmaxf(fmaxf(fmaxf(s[2][0], s[2][1]), fmaxf(s[2][2], s[2][3])),
                         fmaxf(fmaxf(s[3][0], s[3][1]), fmaxf(s[3][2], s[3][3]))));
    tm = fmaxf(tm, __shfl_xor(tm, 16));
    tm = fmaxf(tm, __shfl_xor(tm, 32));
    // speculative exps against current m (defer-max)
    float p[4][4];
    #pragma unroll
    for (int t = 0; t < 4; t++)
      #pragma unroll
      for (int r = 0; r < 4; r++)
        p[t][r] = __builtin_amdgcn_exp2f(s[t][r] - m);
    float rs = ((p[0][0] + p[0][1]) + (p[0][2] + p[0][3])) +
               ((p[1][0] + p[1][1]) + (p[1][2] + p[1][3])) +
               ((p[2][0] + p[2][1]) + (p[2][2] + p[2][3])) +
               ((p[3][0] + p[3][1]) + (p[3][2] + p[3][3]));
    if (__any(tm > m + 8.f)) {   // rare: max drifted past defer threshold
      float mn = fmaxf(m, tm);
      float sc = __builtin_amdgcn_exp2f(m - mn);
      #pragma unroll
      for (int t = 0; t < 4; t++)
        #pragma unroll
        for (int r = 0; r < 4; r++) p[t][r] *= sc;
      rs *= sc;
      l *= sc;
      if (q4 == 0) SCb[wave][l16] = sc;
      floatx4 sv = *(const floatx4*)&SCb[wave][q4 * 4];
      #pragma unroll
      for (int r = 0; r < 4; r++) { o0[r] *= sv[r]; o1[r] *= sv[r]; }
      m = mn;
    }
    rs += __shfl_xor(rs, 16);
    rs += __shfl_xor(rs, 32);
    l += rs;
    // P stage: kv contiguous per lane -> b64 writes (per-wave buffer, no barrier needed)
    #pragma unroll
    for (int t = 0; t < 4; t++) {
      uint2 w;
      w.x = pkbf(p[t][0], p[t][1]);
      w.y = pkbf(p[t][2], p[t][3]);
      *(uint2*)&P[wave][l16][t * 16 + q4 * 4] = w;
    }
    bf16x8 pf0 = *(const bf16x8*)&P[wave][l16][q4 * 8];
    bf16x8 pf1 = *(const bf16x8*)&P[wave][l16][32 + q4 * 8];
    // V frags from LDS: row d = l16(+16), orig kv-chunk ks*4+q4 at position ^(row&7)
    bf16x8 v00 = *(const bf16x8*)&Vs[cur][l16][((q4 ^ vx)) * 8];
    bf16x8 v01 = *(const bf16x8*)&Vs[cur][l16 + 16][((q4 ^ vx)) * 8];
    bf16x8 v10 = *(const bf16x8*)&Vs[cur][l16][(((4 + q4) ^ vx)) * 8];
    bf16x8 v11 = *(const bf16x8*)&Vs[cur][l16 + 16][(((4 + q4) ^ vx)) * 8];
    __builtin_amdgcn_s_setprio(1);
    o0 = MFMA16(pf0, v00, o0, 0, 0, 0);
    o1 = MFMA16(pf0, v01, o1, 0, 0, 0);
    o0 = MFMA16(pf1, v10, o0, 0, 0, 0);
    o1 = MFMA16(pf1, v11, o1, 0, 0, 0);
    __builtin_amdgcn_s_setprio(0);
    // stage next tile into the other buffer; bias rotate
    if (it < 8) {
      *(bf16x8*)(ksd + nx) = kNr;
      *(bf16x8*)(vsd + nx) = vNr;
      #pragma unroll
      for (int t = 0; t < 4; t++) bfr[t] = bn[t];
    }
    asm volatile("s_waitcnt lgkmcnt(0)" ::: "memory");
    __builtin_amdgcn_sched_barrier(0);
    __builtin_amdgcn_s_barrier();
    __builtin_amdgcn_sched_barrier(0);
  }
  // normalize: 1/l lives in q=l16 rep; redistribute to O-row rep via per-wave LDS broadcast
  float invl = 1.f / l;
  if (q4 == 0) SCb[wave][l16] = invl;
  floatx4 iv = *(const floatx4*)&SCb[wave][q4 * 4];
  bf16* op = O + ((size_t)b * 256 + q0 + q4 * 4) * 256 + h * 32;
  #pragma unroll
  for (int r = 0; r < 4; r++) {
    op[(size_t)r * 256 + l16]      = __float2bfloat16(o0[r] * iv[r]);
    op[(size_t)r * 256 + 16 + l16] = __float2bfloat16(o1[r] * iv[r]);
  }
}

extern "C" void kernel_launch(void* const* d_in, const int* in_sizes, int n_in,
                              void* d_out, int out_size, void* d_ws, size_t ws_size,
                              hipStream_t stream) {
  const void* q_w    = d_in[0];
  const void* kv_w   = d_in[1];
  const void* q_Wm   = d_in[2];
  const void* q_b    = d_in[3];
  const void* kv_Wm  = d_in[4];
  const void* kv_b   = d_in[5];
  const void* proj_Wm= d_in[6];
  const void* proj_b = d_in[7];
  const void* btab   = d_in[8];
  const int*  relidx = (const int*)d_in[9];

  // ---- workspace layout (element offsets are dtype-agnostic) ----
  // flag 256 | WqT 131072 | WkvT 262144 | WpT 131072 | biasFb 2359296 | chunk buffers
  const size_t FIXED = 256 + 131072 + 262144 + 131072 + 2359296;  // 2,883,840
  int W = 2;
  {
    const int cand[8] = {256, 128, 64, 32, 16, 8, 4, 2};
    for (int i = 0; i < 8; i++) {
      if (ws_size >= FIXED + (size_t)cand[i] * 851968ULL) { W = cand[i]; break; }
    }
  }
  const int NCH = 256 / W;

  char* ws = (char*)d_ws;
  int*  flag  = (int*)(ws);
  bf16* WqT   = (bf16*)(ws + 256);
  bf16* WkvT  = (bf16*)(ws + 131328);
  bf16* WpT   = (bf16*)(ws + 393472);
  bf16* biasFb= (bf16*)(ws + 524544);
  char* cb    = ws + FIXED;
  const size_t qsz = (size_t)W * 131072ULL;   // W*256*256*2
  const size_t ksz = (size_t)W * 294912ULL;   // W*576*256*2
  bf16* Qs   = (bf16*)(cb);
  bf16* Kb   = (bf16*)(cb + qsz);
  bf16* Vt   = (bf16*)(cb + qsz + ksz);
  bf16* Obuf = (bf16*)(cb + qsz + 2 * ksz);

  detect_dtype<<<1, 64, 0, stream>>>((const unsigned short*)q_w, flag);
  transpose_w<<<dim3(8, 8),  256, 0, stream>>>(q_Wm,   WqT,  256, flag);
  transpose_w<<<dim3(16, 8), 256, 0, stream>>>(kv_Wm,  WkvT, 512, flag);
  transpose_w<<<dim3(8, 8),  256, 0, stream>>>(proj_Wm,WpT,  256, flag);
  bias_expand<<<576, 256, 0, stream>>>(btab, relidx, biasFb, flag);

  for (int c = 0; c < NCH; c++) {
    const size_t qoff = (size_t)c * W * 65536;    // elements
    const size_t koff = (size_t)c * W * 147456;   // elements
    // q projection (+scale*log2e): M = W*256, N = 256 -> 1-D grid, n-fastest
    gemm_bt<1><<<4 * W, 256, 0, stream>>>(q_w, qoff, WqT, q_b, Qs, 0, nullptr, flag);
    // kv projection: M = W*576, N = 512 -> nwg = 18W
    gemm_bt<2><<<18 * W, 256, 0, stream>>>(kv_w, koff, WkvT, kv_b, Kb, 0, Vt, flag);
    // attention: W windows * 8 heads * 4 q-chunks
    attn<<<W * 32, 256, 0, stream>>>(Qs, Kb, Vt, biasFb, Obuf, W * 32);
    // output projection: M = W*256, N = 256, store dtype per flag
    gemm_bt<0><<<4 * W, 256, 0, stream>>>(Obuf, 0, WpT, proj_b, d_out, qoff, nullptr, flag);
  }
}